// Round 1
// baseline (4773.776 us; speedup 1.0000x reference)
//
#include <hip/hip_runtime.h>

#define H 192
#define W 192
#define HW (H*W)
#define G 32          // feature/ctx channels
#define C 64          // x channels
#define C1 68         // conv1 out channels
#define B 6           // output batches
#define NB 2          // distinct ctx batches
#define OUTC 260      // 68 + 3*64

// K1: img_ctx[b][o][p] = b_ctx[o] + sum_k w_ctx[o][k] * feature[b][k][p], b in 0..1
__global__ __launch_bounds__(256) void ctx_kernel(
    const float* __restrict__ feature, const float* __restrict__ w_ctx,
    const float* __restrict__ b_ctx, float* __restrict__ ctx)
{
    int p = blockIdx.x * 256 + threadIdx.x;
    int b = blockIdx.y;
    float f[G];
    const float* fp = feature + (size_t)b * G * HW + p;
#pragma unroll
    for (int k = 0; k < G; k++) f[k] = fp[k * HW];
    float* op = ctx + (size_t)b * G * HW + p;
    for (int o = 0; o < G; o++) {
        float acc = b_ctx[o];
#pragma unroll
        for (int k = 0; k < G; k++) acc += w_ctx[o * G + k] * f[k];
        op[o * HW] = acc;
    }
}

// K2: out[b][o][p] = b1[o] + sum_c w1[o][c] * x[b][c][p], o in 0..67
// x channels: 0..31 = ctx[b/3], 32..63 = extra[b]
__global__ __launch_bounds__(256) void conv1_kernel(
    const float* __restrict__ ctx, const float* __restrict__ extra,
    const float* __restrict__ w1, const float* __restrict__ b1,
    float* __restrict__ out)
{
    int p = blockIdx.x * 256 + threadIdx.x;
    int b = blockIdx.y;
    float xv[C];
    const float* cp = ctx + (size_t)(b / 3) * G * HW + p;
#pragma unroll
    for (int k = 0; k < G; k++) xv[k] = cp[k * HW];
    const float* ep = extra + (size_t)b * G * HW + p;
#pragma unroll
    for (int k = 0; k < G; k++) xv[G + k] = ep[k * HW];
    float* op = out + (size_t)b * OUTC * HW + p;
    for (int o = 0; o < C1; o++) {
        float acc = b1[o];
#pragma unroll
        for (int k = 0; k < C; k++) acc += w1[o * C + k] * xv[k];
        op[o * HW] = acc;
    }
}

// K3: horizontal clamped sliding sums of x and x^2 for one batch.
// hs1/hs2: [C][H][W]
__global__ __launch_bounds__(192) void hbox_kernel(
    const float* __restrict__ ctx, const float* __restrict__ extra,
    int b, int half,
    float* __restrict__ hs1, float* __restrict__ hs2)
{
    __shared__ float row[W];
    int w = threadIdx.x;
    int ch = blockIdx.x;          // 0 .. C*H-1
    int c = ch / H;
    int h = ch % H;
    const float* src = (c < G)
        ? (ctx + ((size_t)(b / 3) * G + c) * HW + (size_t)h * W)
        : (extra + ((size_t)b * G + (c - G)) * HW + (size_t)h * W);
    row[w] = src[w];
    __syncthreads();
    int x0 = max(w - half, 0);
    int x1 = min(w + half, W - 1);
    float s1 = 0.f, s2 = 0.f;
    for (int x = x0; x <= x1; x++) { float v = row[x]; s1 += v; s2 += v * v; }
    int idx = c * HW + h * W + w;
    hs1[idx] = s1;
    hs2[idx] = s2;
}

// K4: vertical clamped sums -> mean/var -> 1x1 conv (128->64) -> out slice
__global__ __launch_bounds__(256) void vconv_kernel(
    const float* __restrict__ hs1, const float* __restrict__ hs2,
    const float* __restrict__ wsc, const float* __restrict__ bsc,
    int b, int half, int co,
    float* __restrict__ out)
{
    int p = blockIdx.x * 256 + threadIdx.x;
    int h = p / W;
    int w = p % W;
    int y0 = max(h - half, 0);
    int y1 = min(h + half, H - 1);
    int x0 = max(w - half, 0);
    int x1 = min(w + half, W - 1);
    float inv_area = 1.0f / (float)((y1 - y0 + 1) * (x1 - x0 + 1));

    float acc[C];
#pragma unroll
    for (int o = 0; o < C; o++) acc[o] = 0.f;

    for (int c = 0; c < C; c++) {
        const float* p1 = hs1 + (size_t)c * HW + (size_t)y0 * W + w;
        const float* p2 = hs2 + (size_t)c * HW + (size_t)y0 * W + w;
        float s1 = 0.f, s2 = 0.f;
        for (int y = y0; y <= y1; y++) { s1 += *p1; s2 += *p2; p1 += W; p2 += W; }
        float mean = s1 * inv_area;
        float var  = s2 * inv_area - mean * mean;
#pragma unroll
        for (int o = 0; o < C; o++)
            acc[o] += wsc[o * 2 * C + c] * mean + wsc[o * 2 * C + C + c] * var;
    }

    float* op = out + (size_t)b * OUTC * HW + (size_t)co * HW + p;
#pragma unroll
    for (int o = 0; o < C; o++) op[o * HW] = acc[o] + bsc[o];
}

extern "C" void kernel_launch(void* const* d_in, const int* in_sizes, int n_in,
                              void* d_out, int out_size, void* d_ws, size_t ws_size,
                              hipStream_t stream) {
    const float* feature = (const float*)d_in[0];
    const float* extra   = (const float*)d_in[1];
    const float* w_ctx   = (const float*)d_in[2];
    const float* b_ctx   = (const float*)d_in[3];
    const float* w1      = (const float*)d_in[4];
    const float* b1      = (const float*)d_in[5];
    const float* w_s[3]  = {(const float*)d_in[6], (const float*)d_in[8], (const float*)d_in[10]};
    const float* b_s[3]  = {(const float*)d_in[7], (const float*)d_in[9], (const float*)d_in[11]};
    float* out = (float*)d_out;

    float* ctx = (float*)d_ws;                      // NB*G*HW floats
    float* hs1 = ctx + (size_t)NB * G * HW;         // C*HW floats
    float* hs2 = hs1 + (size_t)C * HW;              // C*HW floats

    ctx_kernel<<<dim3(HW / 256, NB), 256, 0, stream>>>(feature, w_ctx, b_ctx, ctx);
    conv1_kernel<<<dim3(HW / 256, B), 256, 0, stream>>>(ctx, extra, w1, b1, out);

    const int halves[3] = {2, 4, 8};
    for (int si = 0; si < 3; si++) {
        for (int b = 0; b < B; b++) {
            hbox_kernel<<<dim3(C * H), W, 0, stream>>>(ctx, extra, b, halves[si], hs1, hs2);
            vconv_kernel<<<dim3(HW / 256), 256, 0, stream>>>(
                hs1, hs2, w_s[si], b_s[si], b, halves[si], C1 + si * C, out);
        }
    }
}

// Round 2
// 720.259 us; speedup vs baseline: 6.6279x; 6.6279x over previous
//
#include <hip/hip_runtime.h>

#define H 192
#define W 192
#define HW (H*W)
#define G 32          // feature/ctx channels
#define C 64          // x channels
#define C2 128        // mean+var channels
#define C1 68         // conv1 out channels
#define B 6           // output batches
#define NB 2          // distinct ctx batches
#define OUTC 260      // 68 + 3*64
#define STRIP 48      // rows per mv block

// K1: img_ctx[b][o][p] = b_ctx[o] + sum_k w_ctx[o][k] * feature[b][k][p], b in 0..1
__global__ __launch_bounds__(256) void ctx_kernel(
    const float* __restrict__ feature, const float* __restrict__ w_ctx,
    const float* __restrict__ b_ctx, float* __restrict__ ctx)
{
    int p = blockIdx.x * 256 + threadIdx.x;
    int b = blockIdx.y;
    float f[G];
    const float* fp = feature + (size_t)b * G * HW + p;
#pragma unroll
    for (int k = 0; k < G; k++) f[k] = fp[k * HW];
    float* op = ctx + (size_t)b * G * HW + p;
    for (int o = 0; o < G; o++) {
        float acc = b_ctx[o];
#pragma unroll
        for (int k = 0; k < G; k++) acc += w_ctx[o * G + k] * f[k];
        op[o * HW] = acc;
    }
}

// K2: out[b][o][p] = b1[o] + sum_c w1[o][c] * x[b][c][p], o in 0..67
__global__ __launch_bounds__(256) void conv1_kernel(
    const float* __restrict__ ctx, const float* __restrict__ extra,
    const float* __restrict__ w1, const float* __restrict__ b1,
    float* __restrict__ out)
{
    int p = blockIdx.x * 256 + threadIdx.x;
    int b = blockIdx.y;
    float xv[C];
    const float* cp = ctx + (size_t)(b / 3) * G * HW + p;
#pragma unroll
    for (int k = 0; k < G; k++) xv[k] = cp[k * HW];
    const float* ep = extra + (size_t)b * G * HW + p;
#pragma unroll
    for (int k = 0; k < G; k++) xv[G + k] = ep[k * HW];
    float* op = out + (size_t)b * OUTC * HW + p;
    for (int o = 0; o < C1; o++) {
        float acc = b1[o];
#pragma unroll
        for (int k = 0; k < C; k++) acc += w1[o * C + k] * xv[k];
        op[o * HW] = acc;
    }
}

// transpose [OC][IC] -> [IC][OC]
__global__ __launch_bounds__(256) void transpose_w_kernel(
    const float* __restrict__ wsrc, float* __restrict__ wT, int oc, int ic)
{
    int i = blockIdx.x * 256 + threadIdx.x;
    if (i >= oc * ic) return;
    int o = i / ic, c = i % ic;
    wT[c * oc + o] = wsrc[i];
}

// K3: mean/var via vertical running sums + horizontal LDS window.
// grid: (C, H/STRIP, nb) ; block: W threads (one per column)
// data batch = bbase + blockIdx.z, mv buffer slot = blockIdx.z
__global__ __launch_bounds__(192) void mv_kernel(
    const float* __restrict__ ctx, const float* __restrict__ extra,
    int half, int bbase, float* __restrict__ mv)
{
    __shared__ float ls1[2][W];
    __shared__ float ls2[2][W];
    int w = threadIdx.x;
    int c = blockIdx.x;
    int s = blockIdx.y;
    int bz = blockIdx.z;
    int b = bbase + bz;
    const float* src = (c < G)
        ? (ctx + ((size_t)(b / 3) * G + c) * HW)
        : (extra + ((size_t)b * G + (c - G)) * HW);

    int h0 = s * STRIP;
    // init running vertical window for h0
    int ya = max(h0 - half, 0);
    int yb = min(h0 + half, H - 1);
    float s1 = 0.f, s2 = 0.f;
    for (int y = ya; y <= yb; y++) { float v = src[y * W + w]; s1 += v; s2 += v * v; }

    int x0 = max(w - half, 0);
    int x1 = min(w + half, W - 1);
    float ncols = (float)(x1 - x0 + 1);

    size_t obase = ((size_t)bz * C2 + c) * HW;

    for (int h = h0; h < h0 + STRIP; h++) {
        if (h > h0) {
            int yadd = h + half;
            int ysub = h - half - 1;
            if (yadd <= H - 1) { float v = src[yadd * W + w]; s1 += v; s2 += v * v; }
            if (ysub >= 0)     { float v = src[ysub * W + w]; s1 -= v; s2 -= v * v; }
        }
        int buf = h & 1;
        ls1[buf][w] = s1;
        ls2[buf][w] = s2;
        __syncthreads();
        float t1 = 0.f, t2 = 0.f;
        for (int x = x0; x <= x1; x++) { t1 += ls1[buf][x]; t2 += ls2[buf][x]; }
        int nrows = min(h + half, H - 1) - max(h - half, 0) + 1;
        float inv_area = 1.0f / ((float)nrows * ncols);
        float mean = t1 * inv_area;
        float var  = t2 * inv_area - mean * mean;
        mv[obase + h * W + w] = mean;
        mv[obase + (size_t)C * HW + h * W + w] = var;
    }
}

// K4: 1x1 conv 128->64 over mv, transposed weights wT[c][64]
// grid: (HW/256, nb) ; data batch = bbase + blockIdx.y, mv slot = blockIdx.y
__global__ __launch_bounds__(256) void sconv_kernel(
    const float* __restrict__ mv, const float* __restrict__ wT,
    const float* __restrict__ bsc, int bbase, int co, float* __restrict__ out)
{
    int p = blockIdx.x * 256 + threadIdx.x;
    int bz = blockIdx.y;
    int b = bbase + bz;
    const float* xp = mv + (size_t)bz * C2 * HW + p;
    float acc[C];
#pragma unroll
    for (int o = 0; o < C; o++) acc[o] = 0.f;
#pragma unroll 2
    for (int c = 0; c < C2; c++) {
        float v = xp[(size_t)c * HW];
        const float* wrow = wT + c * C;
#pragma unroll
        for (int o = 0; o < C; o++) acc[o] += wrow[o] * v;
    }
    float* op = out + ((size_t)b * OUTC + co) * HW + p;
#pragma unroll
    for (int o = 0; o < C; o++) op[o * HW] = acc[o] + bsc[o];
}

extern "C" void kernel_launch(void* const* d_in, const int* in_sizes, int n_in,
                              void* d_out, int out_size, void* d_ws, size_t ws_size,
                              hipStream_t stream) {
    const float* feature = (const float*)d_in[0];
    const float* extra   = (const float*)d_in[1];
    const float* w_ctx   = (const float*)d_in[2];
    const float* b_ctx   = (const float*)d_in[3];
    const float* w1      = (const float*)d_in[4];
    const float* b1      = (const float*)d_in[5];
    const float* w_s[3]  = {(const float*)d_in[6], (const float*)d_in[8], (const float*)d_in[10]};
    const float* b_s[3]  = {(const float*)d_in[7], (const float*)d_in[9], (const float*)d_in[11]};
    float* out = (float*)d_out;

    // ws layout (floats)
    float* ctx = (float*)d_ws;                       // NB*G*HW
    float* wT  = ctx + (size_t)NB * G * HW;          // 3 * C2*C
    float* mv  = wT + 3 * C2 * C;                    // nb * C2 * HW

    size_t base_bytes = ((size_t)NB * G * HW + 3 * C2 * C) * 4;
    size_t mv_full = (size_t)B * C2 * HW * 4;
    bool batched = ws_size >= base_bytes + mv_full;

    ctx_kernel<<<dim3(HW / 256, NB), 256, 0, stream>>>(feature, w_ctx, b_ctx, ctx);
    conv1_kernel<<<dim3(HW / 256, B), 256, 0, stream>>>(ctx, extra, w1, b1, out);

    for (int si = 0; si < 3; si++) {
        transpose_w_kernel<<<dim3((C2 * C + 255) / 256), 256, 0, stream>>>(
            w_s[si], wT + si * C2 * C, C, C2);
    }

    const int halves[3] = {2, 4, 8};
    if (batched) {
        for (int si = 0; si < 3; si++) {
            mv_kernel<<<dim3(C, H / STRIP, B), W, 0, stream>>>(ctx, extra, halves[si], 0, mv);
            sconv_kernel<<<dim3(HW / 256, B), 256, 0, stream>>>(
                mv, wT + si * C2 * C, b_s[si], 0, C1 + si * C, out);
        }
    } else {
        for (int si = 0; si < 3; si++) {
            for (int b = 0; b < B; b++) {
                mv_kernel<<<dim3(C, H / STRIP, 1), W, 0, stream>>>(ctx, extra, halves[si], b, mv);
                sconv_kernel<<<dim3(HW / 256, 1), 256, 0, stream>>>(
                    mv, wT + si * C2 * C, b_s[si], b, C1 + si * C, out);
            }
        }
    }
}